// Round 14
// baseline (407.254 us; speedup 1.0000x reference)
//
#include <hip/hip_runtime.h>

#define Bsz 16
#define Nn  100000
#define Ee  2000000
#define Dd  512
#define Cc  10
#define NB  (Nn * Bsz)
#define NB4 (NB / 4)                            // update threads (float4)
#define NB8 (NB / 8)                            // 200000 gather threads (node,half)
#define NP2 ((NB8 + 255) / 256)                 // 782 gather blocks
#define NBK 196                                 // dst buckets (512 nodes each)
#define BPAD 16                                 // bucket cursor padding (1/64B line)
#define BE   4096                               // bin1/bhist edges per block
#define SEDMAX 12288                            // bin2 LDS staging cap (96 KB)

typedef unsigned short us8 __attribute__((ext_vector_type(8)));

// ---- ordered-uint encoding for float min/max (monotone map) ----
__device__ __forceinline__ unsigned enc_f(float f) {
    unsigned u = __float_as_uint(f);
    return (u & 0x80000000u) ? ~u : (u | 0x80000000u);
}
__device__ __forceinline__ float dec_f(unsigned e) {
    unsigned u = (e & 0x80000000u) ? (e ^ 0x80000000u) : ~e;
    return __uint_as_float(u);
}
// f32 -> bf16 RNE (values are finite; no NaN handling needed)
__device__ __forceinline__ unsigned short tob(float f) {
    unsigned u = __float_as_uint(f);
    return (unsigned short)((u + 0x7FFFu + ((u >> 16) & 1u)) >> 16);
}
__device__ __forceinline__ float tof(unsigned short h) {
    return __uint_as_float((unsigned)h << 16);
}

// LDS-tiled transpose x (B,N) -> xh[n*16+b] in bf16 (3.2 MB: per-XCD L2 fits);
// thr[n]=|nt[n]|; zero bucket counts + last-block ticket counter
__global__ void prep(const float* __restrict__ x, const float* __restrict__ nt,
                     unsigned short* __restrict__ xh, float* __restrict__ thr,
                     int* __restrict__ bcnt, int* __restrict__ ctr) {
    __shared__ float sm[16][65];
    int t = threadIdx.x;
    int n0 = blockIdx.x * 64;
    #pragma unroll
    for (int rep = 0; rep < 4; rep++) {
        int r = rep * 4 + (t >> 6);      // batch row 0..15
        int c = t & 63;                  // node within tile
        int n = n0 + c;
        sm[r][c] = (n < Nn) ? x[r * Nn + n] : 0.0f;
    }
    __syncthreads();
    int nn = t >> 2, bq = t & 3;
    int n = n0 + nn;
    if (n < Nn) {
        ushort4 h;
        h.x = tob(sm[bq * 4 + 0][nn]);
        h.y = tob(sm[bq * 4 + 1][nn]);
        h.z = tob(sm[bq * 4 + 2][nn]);
        h.w = tob(sm[bq * 4 + 3][nn]);
        ((ushort4*)xh)[n * 4 + bq] = h;
    }
    int gid = blockIdx.x * 256 + t;
    if (gid < Nn) thr[gid] = fabsf(nt[gid]);
    if (gid < NBK) bcnt[gid] = 0;
    if (gid == 0) *ctr = 0;
}

// bucket-level histogram: LDS accumulation, <=196 global atomics per block
__global__ void bhist(const int* __restrict__ dstv, int* __restrict__ bcnt) {
    __shared__ int lh[NBK];
    int t = threadIdx.x;
    if (t < NBK) lh[t] = 0;
    __syncthreads();
    int e = blockIdx.x * BE + t;
    #pragma unroll
    for (int j = 0; j < BE / 256; j++, e += 256)
        if (e < Ee) atomicAdd(&lh[dstv[e] >> 9], 1);
    __syncthreads();
    if (t < NBK && lh[t] > 0) atomicAdd(&bcnt[t], lh[t]);
}

// scan 196 bucket counts -> bucket bases + cursors (single block)
__global__ void bscan(const int* __restrict__ bcnt, int* __restrict__ bbase,
                      int* __restrict__ bcur) {
    __shared__ int s[256];
    int t = threadIdx.x;
    int v = (t < NBK) ? bcnt[t] : 0;
    s[t] = v;
    __syncthreads();
    for (int off = 1; off < 256; off <<= 1) {
        int u = (t >= off) ? s[t - off] : 0;
        __syncthreads();
        s[t] += u;
        __syncthreads();
    }
    if (t < NBK) {
        int excl = s[t] - v;
        bbase[t] = excl;
        bcur[t * BPAD] = excl;
    }
    if (t == 0) bbase[NBK] = Ee;
}

// level-1: LDS-staged bucket partition with BURST writes (coalesced copy-out).
__global__ void bin1(const int* __restrict__ srcv, const int* __restrict__ dstv,
                     const float* __restrict__ ew, const float* __restrict__ mult,
                     int* __restrict__ bcur, int2* __restrict__ csr_sw) {
    __shared__ int2  sdat[BE];       // 32 KB
    __shared__ short sbk[BE];        // 8 KB
    __shared__ int   sbase[NBK];     // local (in-block) exclusive base
    __shared__ int   scur[NBK];      // histogram, then scatter cursors
    __shared__ int   sg[NBK];        // global base per bucket
    __shared__ int   ss[256];
    int t = threadIdx.x;
    int e0 = blockIdx.x * BE;
    if (t < NBK) scur[t] = 0;
    __syncthreads();
    // pass A: block-local bucket histogram
    #pragma unroll
    for (int j = 0; j < BE / 256; j++) {
        int e = e0 + t + j * 256;
        if (e < Ee) atomicAdd(&scur[dstv[e] >> 9], 1);
    }
    __syncthreads();
    int v = (t < NBK) ? scur[t] : 0;
    ss[t] = v;
    __syncthreads();
    for (int off = 1; off < 256; off <<= 1) {
        int u = (t >= off) ? ss[t - off] : 0;
        __syncthreads();
        ss[t] += u;
        __syncthreads();
    }
    int excl = ss[t] - v;
    if (t < NBK) {
        if (v > 0) sg[t] = atomicAdd(&bcur[t * BPAD], v);
        sbase[t] = excl;
        scur[t]  = excl;
    }
    __syncthreads();
    // pass B: re-read edges (L2-hot), compute w, scatter into LDS by bucket
    #pragma unroll
    for (int j = 0; j < BE / 256; j++) {
        int e = e0 + t + j * 256;
        if (e < Ee) {
            int d = dstv[e];
            int bk = d >> 9;
            int pos = atomicAdd(&scur[bk], 1);
            int2 p;
            p.x = srcv[e] | ((d & 511) << 17);
            p.y = __float_as_int(ew[e] * tanhf(mult[e]));
            sdat[pos] = p;
            sbk[pos] = (short)bk;
        }
    }
    __syncthreads();
    // pass C: burst copy-out
    int cnt = min(Ee - e0, BE);
    for (int s = t; s < cnt; s += 256) {
        int bk = sbk[s];
        csr_sw[sg[bk] + (s - sbase[bk])] = sdat[s];
    }
}

// level-2: per 512-node bucket: stage edges in LDS, per-node hist + scan in
// LDS, write row[] coalesced, counting-sort in place.
__global__ __launch_bounds__(512) void bin2(const int* __restrict__ bbase,
                                            int2* __restrict__ csr_sw,
                                            int* __restrict__ row) {
    __shared__ int2 sed[SEDMAX];     // 96 KB
    __shared__ int  lh[512];         // hist -> cursors
    __shared__ int  lscan[512];
    int b = blockIdx.x;
    int n0 = b * 512;
    int n1 = min(n0 + 512, Nn);
    int e0 = bbase[b], e1 = bbase[b + 1];
    int cnt = e1 - e0;
    if (cnt > SEDMAX) cnt = SEDMAX;   // statistically unreachable (+20 sigma)
    int t = threadIdx.x;
    lh[t] = 0;
    for (int s = t; s < cnt; s += 512) sed[s] = csr_sw[e0 + s];
    __syncthreads();
    for (int s = t; s < cnt; s += 512) atomicAdd(&lh[(sed[s].x >> 17) & 511], 1);
    __syncthreads();
    int v = lh[t];
    lscan[t] = v;
    __syncthreads();
    for (int off = 1; off < 512; off <<= 1) {
        int u = (t >= off) ? lscan[t - off] : 0;
        __syncthreads();
        lscan[t] += u;
        __syncthreads();
    }
    int excl = lscan[t] - v;
    int n = n0 + t;
    if (n < n1) row[n] = e0 + excl;
    if (b == NBK - 1 && t == 0) row[Nn] = Ee;
    lh[t] = excl;                    // local cursors
    __syncthreads();
    for (int s = t; s < cnt; s += 512) {
        int2 p = sed[s];
        int nl = (p.x >> 17) & 511;
        int pos = atomicAdd(&lh[nl], 1);
        csr_sw[e0 + pos] = make_int2(p.x & 0x1FFFF, p.y);
    }
}

// thread = (node, half): 8 batch slots per thread, ushort8 (16B) xh loads ->
// 1KB per wave load instruction, CSR loaded by only 2 lanes/node. 8-wide edge
// unroll keeps 8 CSR + 8 xh loads in flight. Min/max folded: per-block
// partials + last-block-done grid reduction (no separate mm_reduce kernel).
__global__ void gather(const int* __restrict__ row, const int2* __restrict__ csr_sw,
                       const unsigned short* __restrict__ xh, float* __restrict__ aggr,
                       uint2* __restrict__ part, unsigned* __restrict__ mm,
                       int* __restrict__ ctr) {
    int i = blockIdx.x * 256 + threadIdx.x;
    bool active = i < NB8;
    float acc[8];
    #pragma unroll
    for (int b = 0; b < 8; b++) acc[b] = 0.0f;
    if (active) {
        int n = i >> 1, h = i & 1;
        int ks = row[n], ke = row[n + 1];
        const us8* x8 = (const us8*)xh;          // index: n*2 + h
        for (int k = ks; k < ke; k += 8) {
            int2 p[8];
            us8  v[8];
            #pragma unroll
            for (int j = 0; j < 8; ++j) {
                int kk = k + j;
                int kc = kk < ke ? kk : ks;          // always a valid index
                p[j] = csr_sw[kc];
                if (kk >= ke) p[j].y = 0;            // 0.0f weight for dead slots
            }
            #pragma unroll
            for (int j = 0; j < 8; ++j) v[j] = x8[p[j].x * 2 + h];
            #pragma unroll
            for (int j = 0; j < 8; ++j) {
                float w = __int_as_float(p[j].y);
                #pragma unroll
                for (int b = 0; b < 8; b++) acc[b] += tof(v[j][b]) * w;
            }
        }
        float4 o0 = make_float4(acc[0], acc[1], acc[2], acc[3]);
        float4 o1 = make_float4(acc[4], acc[5], acc[6], acc[7]);
        ((float4*)aggr)[i * 2]     = o0;
        ((float4*)aggr)[i * 2 + 1] = o1;
    }

    float lmin = INFINITY, lmax = -INFINITY;
    if (active) {
        #pragma unroll
        for (int b = 0; b < 8; b++) {
            lmin = fminf(lmin, acc[b]);
            lmax = fmaxf(lmax, acc[b]);
        }
    }
    #pragma unroll
    for (int off = 32; off > 0; off >>= 1) {
        lmin = fminf(lmin, __shfl_down(lmin, off));
        lmax = fmaxf(lmax, __shfl_down(lmax, off));
    }
    __shared__ float smin[4], smax[4];
    __shared__ int isLast;
    int wid = threadIdx.x >> 6, lane = threadIdx.x & 63;
    if (lane == 0) { smin[wid] = lmin; smax[wid] = lmax; }
    __syncthreads();
    if (threadIdx.x == 0) {
        float m0 = smin[0], M0 = smax[0];
        #pragma unroll
        for (int k = 1; k < 4; k++) { m0 = fminf(m0, smin[k]); M0 = fmaxf(M0, smax[k]); }
        part[blockIdx.x] = make_uint2(enc_f(m0), enc_f(M0));
        __threadfence();                       // partial visible device-wide
        int c = atomicAdd(ctr, 1);             // take ticket
        isLast = (c == (int)gridDim.x - 1);
    }
    __syncthreads();
    if (isLast) {
        __threadfence();                       // acquire all partials
        unsigned umin = 0xFFFFFFFFu, umax = 0u;
        for (int s = threadIdx.x; s < NP2; s += 256) {
            uint2 p = part[s];
            umin = min(umin, p.x);
            umax = max(umax, p.y);
        }
        #pragma unroll
        for (int off = 32; off > 0; off >>= 1) {
            umin = min(umin, __shfl_down(umin, off));
            umax = max(umax, __shfl_down(umax, off));
        }
        __shared__ unsigned smn[4], smx[4];
        if (lane == 0) { smn[wid] = umin; smx[wid] = umax; }
        __syncthreads();
        if (threadIdx.x == 0) {
            #pragma unroll
            for (int k = 1; k < 4; k++) { umin = min(umin, smn[k]); umax = max(umax, smx[k]); }
            mm[0] = umin;
            mm[1] = umax;
            *ctr = 0;                          // re-arm for next pass / replay
        }
    }
}

// sigmoid update. Passes 0-2: write bf16 xh (gather input). Pass 3: write f32
// result IN-PLACE into aggr (read-then-write same element, safe) for final_k.
__global__ void update(float* __restrict__ aggr, const float* __restrict__ thr,
                       const unsigned* __restrict__ mm, unsigned short* __restrict__ xh,
                       int last) {
    int q = blockIdx.x * blockDim.x + threadIdx.x;   // NB/4 quads
    if (q < NB4) {
        float amin = dec_f(mm[0]), amax = dec_f(mm[1]);
        float inv = 1.0f / (amax - amin);
        int n = q >> 2;
        float t = thr[n];
        float4 a = ((const float4*)aggr)[q];
        float4 r;
        r.x = 1.0f / (1.0f + expf(-((a.x - amin) * inv - t)));
        r.y = 1.0f / (1.0f + expf(-((a.y - amin) * inv - t)));
        r.z = 1.0f / (1.0f + expf(-((a.z - amin) * inv - t)));
        r.w = 1.0f / (1.0f + expf(-((a.w - amin) * inv - t)));
        if (last) {
            ((float4*)aggr)[q] = r;
        } else {
            ushort4 h;
            h.x = tob(r.x); h.y = tob(r.y); h.z = tob(r.z); h.w = tob(r.w);
            ((ushort4*)xh)[q] = h;
        }
    }
}

// gather decision nodes (f32, from aggr) + (16x512)@(512x10) matmul
__global__ void final_k(const float* __restrict__ xf, const int* __restrict__ dix,
                        const float* __restrict__ fcw, const float* __restrict__ fcb,
                        float* __restrict__ out) {
    __shared__ float xd[Dd][Bsz];   // 32 KB
    int j = threadIdx.x;
    int n = dix[j];
    #pragma unroll
    for (int b = 0; b < Bsz; b++) xd[j][b] = xf[n * 16 + b];
    __syncthreads();
    if (j < Bsz * Cc) {
        int b = j / Cc, c = j % Cc;
        float acc = fcb[c];
        for (int k = 0; k < Dd; k++) acc += xd[k][b] * fcw[c * Dd + k];
        out[b * Cc + c] = acc;
    }
}

extern "C" void kernel_launch(void* const* d_in, const int* in_sizes, int n_in,
                              void* d_out, int out_size, void* d_ws, size_t ws_size,
                              hipStream_t stream) {
    const float* x    = (const float*)d_in[0];
    const float* ew   = (const float*)d_in[1];
    const float* mult = (const float*)d_in[2];
    const float* nt   = (const float*)d_in[3];
    const float* fcw  = (const float*)d_in[4];
    const float* fcb  = (const float*)d_in[5];
    const int*   ei   = (const int*)d_in[6];
    const int*   dix  = (const int*)d_in[7];
    float* out = (float*)d_out;

    const int* srcv = ei;
    const int* dstv = ei + Ee;

    // workspace layout (~26 MB)
    unsigned short* xh = (unsigned short*)d_ws;  // NB bf16 (3.2 MB)
    float* aggr    = (float*)(xh + NB);          // NB f32
    float* thr     = aggr + NB;                  // Nn
    int2*  csr_sw  = (int2*)(thr + Nn);          // Ee
    uint2* part    = (uint2*)(csr_sw + Ee);      // NP2
    int*   row     = (int*)(part + NP2);         // Nn+1
    int*   bcnt    = row + Nn + 1;               // NBK
    int*   bbase   = bcnt + NBK;                 // NBK+1
    int*   bcur    = bbase + NBK + 1;            // NBK*BPAD
    int*   ctr     = bcur + NBK * BPAD;          // 1
    unsigned* mm   = (unsigned*)(ctr + 1);       // 2

    prep<<<(Nn + 63) / 64, 256, 0, stream>>>(x, nt, xh, thr, bcnt, ctr);
    bhist<<<(Ee + BE - 1) / BE, 256, 0, stream>>>(dstv, bcnt);
    bscan<<<1, 256, 0, stream>>>(bcnt, bbase, bcur);
    bin1<<<(Ee + BE - 1) / BE, 256, 0, stream>>>(srcv, dstv, ew, mult, bcur, csr_sw);
    bin2<<<NBK, 512, 0, stream>>>(bbase, csr_sw, row);

    for (int p = 0; p < 4; p++) {
        gather<<<NP2, 256, 0, stream>>>(row, csr_sw, xh, aggr, part, mm, ctr);
        update<<<(NB4 + 255) / 256, 256, 0, stream>>>(aggr, thr, mm, xh, p == 3);
    }

    final_k<<<1, 512, 0, stream>>>(aggr, dix, fcw, fcb, out);
}